// Round 13
// baseline (108.894 us; speedup 1.0000x reference)
//
#include <hip/hip_runtime.h>
#include <hip/hip_bf16.h>
#include <math.h>

#define B_  8
#define T_  2048
#define E_  1024
#define H_  128
#define BT_ (B_*T_)
#define TH_ (T_*H_)

typedef unsigned short u16;
typedef __attribute__((ext_vector_type(8))) unsigned short u16x8;  // 16B
typedef __attribute__((ext_vector_type(8))) short bf16x8;          // MFMA A/B frag
typedef __attribute__((ext_vector_type(4))) float f32x4;           // MFMA C/D frag

__device__ __forceinline__ u16 f2bf(float f) {
    union { float f; unsigned int u; } a;
    a.f = f;
    unsigned int r = a.u + 0x7FFFu + ((a.u >> 16) & 1u);   // RNE
    return (u16)(r >> 16);
}

// ---------------------------------------------------------------------------
// prep: W[e][h] fp32  ->  Wt[w][h][e] bf16   (verified round 5)
// ---------------------------------------------------------------------------
__global__ __launch_bounds__(256) void prep_kernel(
    const float* __restrict__ Wk,
    const float* __restrict__ Wq,
    const float* __restrict__ Wv,
    u16* __restrict__ Wt)
{
    __shared__ u16 Tl[128][136];

    const int w  = blockIdx.x >> 3;
    const int et = blockIdx.x & 7;
    const float* __restrict__ W = (w == 0) ? Wk : (w == 1) ? Wq : Wv;
    const int tid = threadIdx.x;

    #pragma unroll
    for (int i = 0; i < 16; ++i) {
        int q = tid + i * 256;
        int e = q >> 5, hc = q & 31;
        float4 v = *reinterpret_cast<const float4*>(
            &W[(size_t)(et * 128 + e) * H_ + hc * 4]);
        Tl[hc * 4 + 0][e] = f2bf(v.x);
        Tl[hc * 4 + 1][e] = f2bf(v.y);
        Tl[hc * 4 + 2][e] = f2bf(v.z);
        Tl[hc * 4 + 3][e] = f2bf(v.w);
    }
    __syncthreads();

    #pragma unroll
    for (int i = 0; i < 8; ++i) {
        int q = tid + i * 256;
        int h = q >> 4, ec = q & 15;
        *reinterpret_cast<u16x8*>(
            &Wt[(size_t)w * (H_ * E_) + (size_t)h * E_ + et * 128 + ec * 8]) =
            *reinterpret_cast<const u16x8*>(&Tl[h][ec * 8]);
    }
}

// ---------------------------------------------------------------------------
// proj_mfma: out[t][h] = x[t][:] . W[:,h]  via bf16 MFMA (verified round 5)
// ---------------------------------------------------------------------------
__global__ __launch_bounds__(256) void proj_mfma(
    const float* __restrict__ x,
    const u16* __restrict__ Wt,
    u16* __restrict__ k_out,
    u16* __restrict__ q_out,
    u16* __restrict__ vt_out)
{
    __shared__ __align__(16) u16 S[13824];   // As[64][72] @0 | Bs[128][72] @4608
    u16* As = S;
    u16* Bs = S + 4608;

    const int row0 = blockIdx.x * 64;
    const int w    = blockIdx.z;
    const int tid  = threadIdx.x;
    const int wave = tid >> 6;
    const int lane = tid & 63;
    const int l15  = lane & 15;
    const int g    = lane >> 4;
    const int wm   = wave >> 1;
    const int wn   = wave & 1;

    f32x4 acc[2][4];
    #pragma unroll
    for (int m = 0; m < 2; ++m)
        #pragma unroll
        for (int n = 0; n < 4; ++n) acc[m][n] = (f32x4){0.f, 0.f, 0.f, 0.f};

    const u16* WtW = Wt + (size_t)w * (H_ * E_);

    for (int ek = 0; ek < 16; ++ek) {
        __syncthreads();
        #pragma unroll
        for (int i = 0; i < 4; ++i) {
            int q = tid + i * 256;
            int r = q >> 4, c4 = q & 15;
            float4 v = *reinterpret_cast<const float4*>(
                &x[(size_t)(row0 + r) * E_ + ek * 64 + c4 * 4]);
            ushort4 h4;
            h4.x = f2bf(v.x); h4.y = f2bf(v.y);
            h4.z = f2bf(v.z); h4.w = f2bf(v.w);
            *reinterpret_cast<ushort4*>(&As[r * 72 + c4 * 4]) = h4;
        }
        #pragma unroll
        for (int i = 0; i < 4; ++i) {
            int q = tid + i * 256;
            int h = q >> 3, c8 = q & 7;
            *reinterpret_cast<u16x8*>(&Bs[h * 72 + c8 * 8]) =
                *reinterpret_cast<const u16x8*>(
                    &WtW[(size_t)h * E_ + ek * 64 + c8 * 8]);
        }
        __syncthreads();

        #pragma unroll
        for (int kk = 0; kk < 2; ++kk) {
            bf16x8 af[2];
            #pragma unroll
            for (int m = 0; m < 2; ++m)
                af[m] = *reinterpret_cast<const bf16x8*>(
                    &As[(wm * 32 + m * 16 + l15) * 72 + kk * 32 + g * 8]);
            #pragma unroll
            for (int n = 0; n < 4; ++n) {
                bf16x8 bfr = *reinterpret_cast<const bf16x8*>(
                    &Bs[(wn * 64 + n * 16 + l15) * 72 + kk * 32 + g * 8]);
                #pragma unroll
                for (int m = 0; m < 2; ++m)
                    acc[m][n] = __builtin_amdgcn_mfma_f32_16x16x32_bf16(
                        af[m], bfr, acc[m][n], 0, 0, 0);
            }
        }
    }
    __syncthreads();

    if (w < 2) {
        #pragma unroll
        for (int m = 0; m < 2; ++m)
            #pragma unroll
            for (int n = 0; n < 4; ++n)
                #pragma unroll
                for (int r = 0; r < 4; ++r)
                    S[(wm * 32 + m * 16 + g * 4 + r) * 136 +
                      wn * 64 + n * 16 + l15] = f2bf(acc[m][n][r]);
        __syncthreads();
        u16* __restrict__ outp = (w == 0) ? k_out : q_out;
        #pragma unroll
        for (int i = 0; i < 4; ++i) {
            int q = tid + i * 256;
            int r = q >> 4, c8 = q & 15;
            *reinterpret_cast<u16x8*>(
                &outp[(size_t)(row0 + r) * H_ + c8 * 8]) =
                *reinterpret_cast<const u16x8*>(&S[r * 136 + c8 * 8]);
        }
    } else {
        #pragma unroll
        for (int m = 0; m < 2; ++m)
            #pragma unroll
            for (int n = 0; n < 4; ++n) {
                ushort4 h4;
                h4.x = f2bf(acc[m][n][0]); h4.y = f2bf(acc[m][n][1]);
                h4.z = f2bf(acc[m][n][2]); h4.w = f2bf(acc[m][n][3]);
                *reinterpret_cast<ushort4*>(
                    &S[(wn * 64 + n * 16 + l15) * 72 +
                       wm * 32 + m * 16 + g * 4]) = h4;
            }
        __syncthreads();
        const int vb = row0 >> 11;
        const int t0 = row0 & 2047;
        #pragma unroll
        for (int i = 0; i < 4; ++i) {
            int q = tid + i * 256;
            int h = q >> 3, c8 = q & 7;
            *reinterpret_cast<u16x8*>(
                &vt_out[(size_t)vb * TH_ + (size_t)h * T_ + t0 + c8 * 8]) =
                *reinterpret_cast<const u16x8*>(&S[h * 72 + c8 * 8]);
        }
    }
}

// ---------------------------------------------------------------------------
// Flash attention, bf16 MFMA — SHARED-TILE blocks with balanced causal pair.
// Block = 512 thr (8 waves). Waves 0-3: row-tile jt=p (64 rows, 16/wave);
// waves 4-7: row-tile jt=31-p. ALL waves consume the same staged K/V s-tile
// sequence 0..31-p; per-block compute = (p+1)+(32-p) = 33 tile-units, same
// for every block -> no stragglers. LDS: K[64][136] + V^T[128][88] (verified
// round-4 layouts) + per-wave P[8][16][88]. T14 staging: next tile global->
// regs before compute, regs->LDS after barrier. No split-s, no merge.
// grid: 128 = 8 batches (low bits, XCD affinity) x 16 pairs.
// ---------------------------------------------------------------------------
__global__ __launch_bounds__(512) void attn_mfma(
    const u16* __restrict__ qg,
    const u16* __restrict__ kg,
    const u16* __restrict__ vtg,
    float* __restrict__ out)
{
    __shared__ __align__(16) u16 Klds[64][136];
    __shared__ __align__(16) u16 Vlds[128][88];
    __shared__ __align__(16) u16 Plds[8][16][88];

    const int tid  = threadIdx.x;
    const int wave = tid >> 6;           // 0..7
    const int lane = tid & 63;
    const int l15  = lane & 15;
    const int g    = lane >> 4;          // 0..3

    const int b  = blockIdx.x & 7;               // batch -> XCD affinity
    const int p  = blockIdx.x >> 3;              // 0..15 (pair index)
    const int jt = (wave < 4) ? p : (31 - p);    // this wave's 64-row tile
    const int qw0 = jt * 64 + (wave & 3) * 16;   // wave's 16 q rows
    const size_t gbase = (size_t)b * TH_;

    const int nt_stage = 32 - p;         // staged s-tiles (covers deeper tile)

    // staging decode (512 thr, 2 chunks each for K and V)
    const int sk = tid >> 4, ck = tid & 15;   // K rows sk, sk+32
    const int hv = tid >> 3, cv = tid & 7;    // V rows hv, hv+64

    // Q fragments: A[row=l15][k = ks*32 + g*8 + j]   (verified round 7)
    bf16x8 qf[4];
    #pragma unroll
    for (int ks = 0; ks < 4; ++ks)
        qf[ks] = *reinterpret_cast<const bf16x8*>(
            &qg[gbase + (size_t)(qw0 + l15) * H_ + ks * 32 + g * 8]);

    f32x4 oacc[8];
    #pragma unroll
    for (int ht = 0; ht < 8; ++ht) oacc[ht] = (f32x4){0.f, 0.f, 0.f, 0.f};
    float m_r[4]  = {-INFINITY, -INFINITY, -INFINITY, -INFINITY};
    float lsum[4] = {0.f, 0.f, 0.f, 0.f};

    const u16* kbat  = kg  + gbase;
    const u16* vtbat = vtg + gbase;

    // ---- prologue: stage tile 0 ----
    #pragma unroll
    for (int t = 0; t < 2; ++t) {
        *reinterpret_cast<u16x8*>(&Klds[sk + t * 32][ck * 8]) =
            *reinterpret_cast<const u16x8*>(
                &kbat[(size_t)(sk + t * 32) * H_ + ck * 8]);
        *reinterpret_cast<u16x8*>(&Vlds[hv + t * 64][cv * 8]) =
            *reinterpret_cast<const u16x8*>(
                &vtbat[(size_t)(hv + t * 64) * T_ + cv * 8]);
    }
    __syncthreads();

    for (int st = 0; st < nt_stage; ++st) {
        const int s0 = st * 64;
        const int s0n = (st + 1 < nt_stage) ? s0 + 64 : s0;   // clamp tail

        // ---- prefetch next tile into regs (latency hides under compute) ----
        u16x8 kreg[2], vreg[2];
        #pragma unroll
        for (int t = 0; t < 2; ++t) {
            kreg[t] = *reinterpret_cast<const u16x8*>(
                &kbat[(size_t)(s0n + sk + t * 32) * H_ + ck * 8]);
            vreg[t] = *reinterpret_cast<const u16x8*>(
                &vtbat[(size_t)(hv + t * 64) * T_ + s0n + cv * 8]);
        }

        if (s0 <= qw0 + 15) {            // causal: this wave still active
            // ---- QK^T: S[16q x 64s], K frags from LDS (verified round 4) ----
            f32x4 sa[4];
            #pragma unroll
            for (int t4 = 0; t4 < 4; ++t4) sa[t4] = (f32x4){0.f, 0.f, 0.f, 0.f};
            __builtin_amdgcn_s_setprio(1);
            #pragma unroll
            for (int ks = 0; ks < 4; ++ks)
                #pragma unroll
                for (int t4 = 0; t4 < 4; ++t4) {
                    bf16x8 kf = *reinterpret_cast<const bf16x8*>(
                        &Klds[t4 * 16 + l15][(ks * 4 + g) * 8]);
                    sa[t4] = __builtin_amdgcn_mfma_f32_16x16x32_bf16(
                        qf[ks], kf, sa[t4], 0, 0, 0);
                }
            __builtin_amdgcn_s_setprio(0);

            // ---- online softmax (verified round 7) ----
            const float scale = 0.088388347648318447f;   // 1/sqrt(128)
            const bool need_mask = (s0 + 63 > qw0);
            float cfac[4];
            #pragma unroll
            for (int r = 0; r < 4; ++r) {
                const int qrow = qw0 + g * 4 + r;
                float sv[4];
                float mx = -INFINITY;
                #pragma unroll
                for (int t4 = 0; t4 < 4; ++t4) {
                    float s = sa[t4][r] * scale;
                    if (need_mask && (s0 + t4 * 16 + l15 > qrow)) s = -INFINITY;
                    sv[t4] = s;
                    mx = fmaxf(mx, s);
                }
                mx = fmaxf(mx, __shfl_xor(mx, 1));
                mx = fmaxf(mx, __shfl_xor(mx, 2));
                mx = fmaxf(mx, __shfl_xor(mx, 4));
                mx = fmaxf(mx, __shfl_xor(mx, 8));
                const float mn = fmaxf(m_r[r], mx);
                const float c  = __expf(m_r[r] - mn);
                float sum = 0.f;
                #pragma unroll
                for (int t4 = 0; t4 < 4; ++t4) {
                    float pv = __expf(sv[t4] - mn);
                    sum += pv;
                    Plds[wave][g * 4 + r][t4 * 16 + l15] = f2bf(pv);
                }
                sum += __shfl_xor(sum, 1);
                sum += __shfl_xor(sum, 2);
                sum += __shfl_xor(sum, 4);
                sum += __shfl_xor(sum, 8);
                lsum[r] = lsum[r] * c + sum;
                m_r[r]  = mn;
                cfac[r] = c;
            }
            #pragma unroll
            for (int ht = 0; ht < 8; ++ht) {
                #pragma unroll
                for (int r = 0; r < 4; ++r) oacc[ht][r] *= cfac[r];
            }

            // ---- PV: V^T frags from LDS (verified round 4) ----
            #pragma unroll
            for (int ks2 = 0; ks2 < 2; ++ks2) {
                bf16x8 pa = *reinterpret_cast<const bf16x8*>(
                    &Plds[wave][l15][ks2 * 32 + g * 8]);
                __builtin_amdgcn_s_setprio(1);
                #pragma unroll
                for (int ht = 0; ht < 8; ++ht) {
                    bf16x8 vf = *reinterpret_cast<const bf16x8*>(
                        &Vlds[ht * 16 + l15][(ks2 * 4 + g) * 8]);
                    oacc[ht] = __builtin_amdgcn_mfma_f32_16x16x32_bf16(
                        pa, vf, oacc[ht], 0, 0, 0);
                }
                __builtin_amdgcn_s_setprio(0);
            }
        }

        __syncthreads();                  // all waves done reading K/V tile
        #pragma unroll
        for (int t = 0; t < 2; ++t) {
            *reinterpret_cast<u16x8*>(&Klds[sk + t * 32][ck * 8]) = kreg[t];
            *reinterpret_cast<u16x8*>(&Vlds[hv + t * 64][cv * 8]) = vreg[t];
        }
        __syncthreads();                  // next tile visible
    }

    // ---- epilogue: rows qw0+g*4+r, cols ht*16+l15 (verified round 7) ----
    #pragma unroll
    for (int r = 0; r < 4; ++r) {
        const float inv = 1.f / lsum[r];
        float* op = &out[gbase + (size_t)(qw0 + g * 4 + r) * H_];
        #pragma unroll
        for (int ht = 0; ht < 8; ++ht)
            op[ht * 16 + l15] = oacc[ht][r] * inv;
    }
}

// ---------------------------------------------------------------------------
extern "C" void kernel_launch(void* const* d_in, const int* in_sizes, int n_in,
                              void* d_out, int out_size, void* d_ws, size_t ws_size,
                              hipStream_t stream) {
    const float* x  = (const float*)d_in[0];
    const float* Wk = (const float*)d_in[1];
    const float* Wq = (const float*)d_in[2];
    const float* Wv = (const float*)d_in[3];
    float* out = (float*)d_out;

    u16* k_ws  = (u16*)d_ws;
    u16* q_ws  = k_ws + (size_t)BT_ * H_;
    u16* vt_ws = q_ws + (size_t)BT_ * H_;
    u16* Wt_ws = vt_ws + (size_t)BT_ * H_;

    prep_kernel<<<dim3(24), 256, 0, stream>>>(Wk, Wq, Wv, Wt_ws);

    dim3 pgrid(BT_ / 64, 1, 3);    // z: 0=k, 1=q, 2=v^T
    proj_mfma<<<pgrid, 256, 0, stream>>>(x, Wt_ws, k_ws, q_ws, vt_ws);

    attn_mfma<<<dim3(128), 512, 0, stream>>>(q_ws, k_ws, vt_ws, out);
}

// Round 14
// 75.505 us; speedup vs baseline: 1.4422x; 1.4422x over previous
//
#include <hip/hip_runtime.h>
#include <hip/hip_bf16.h>
#include <math.h>

#define B_  8
#define T_  2048
#define E_  1024
#define H_  128
#define BT_ (B_*T_)
#define TH_ (T_*H_)

typedef unsigned short u16;
typedef __attribute__((ext_vector_type(8))) unsigned short u16x8;  // 16B
typedef __attribute__((ext_vector_type(8))) short bf16x8;          // MFMA A/B frag
typedef __attribute__((ext_vector_type(4))) float f32x4;           // MFMA C/D frag

__device__ __forceinline__ u16 f2bf(float f) {
    union { float f; unsigned int u; } a;
    a.f = f;
    unsigned int r = a.u + 0x7FFFu + ((a.u >> 16) & 1u);   // RNE
    return (u16)(r >> 16);
}

// ---------------------------------------------------------------------------
// prep: W[e][h] fp32  ->  Wt[w][h][e] bf16   (verified round 5)
// ---------------------------------------------------------------------------
__global__ __launch_bounds__(256) void prep_kernel(
    const float* __restrict__ Wk,
    const float* __restrict__ Wq,
    const float* __restrict__ Wv,
    u16* __restrict__ Wt)
{
    __shared__ u16 Tl[128][136];

    const int w  = blockIdx.x >> 3;
    const int et = blockIdx.x & 7;
    const float* __restrict__ W = (w == 0) ? Wk : (w == 1) ? Wq : Wv;
    const int tid = threadIdx.x;

    #pragma unroll
    for (int i = 0; i < 16; ++i) {
        int q = tid + i * 256;
        int e = q >> 5, hc = q & 31;
        float4 v = *reinterpret_cast<const float4*>(
            &W[(size_t)(et * 128 + e) * H_ + hc * 4]);
        Tl[hc * 4 + 0][e] = f2bf(v.x);
        Tl[hc * 4 + 1][e] = f2bf(v.y);
        Tl[hc * 4 + 2][e] = f2bf(v.z);
        Tl[hc * 4 + 3][e] = f2bf(v.w);
    }
    __syncthreads();

    #pragma unroll
    for (int i = 0; i < 8; ++i) {
        int q = tid + i * 256;
        int h = q >> 4, ec = q & 15;
        *reinterpret_cast<u16x8*>(
            &Wt[(size_t)w * (H_ * E_) + (size_t)h * E_ + et * 128 + ec * 8]) =
            *reinterpret_cast<const u16x8*>(&Tl[h][ec * 8]);
    }
}

// ---------------------------------------------------------------------------
// proj_mfma: out[t][h] = x[t][:] . W[:,h]  via bf16 MFMA (verified round 5)
// ---------------------------------------------------------------------------
__global__ __launch_bounds__(256) void proj_mfma(
    const float* __restrict__ x,
    const u16* __restrict__ Wt,
    u16* __restrict__ k_out,
    u16* __restrict__ q_out,
    u16* __restrict__ vt_out)
{
    __shared__ __align__(16) u16 S[13824];   // As[64][72] @0 | Bs[128][72] @4608
    u16* As = S;
    u16* Bs = S + 4608;

    const int row0 = blockIdx.x * 64;
    const int w    = blockIdx.z;
    const int tid  = threadIdx.x;
    const int wave = tid >> 6;
    const int lane = tid & 63;
    const int l15  = lane & 15;
    const int g    = lane >> 4;
    const int wm   = wave >> 1;
    const int wn   = wave & 1;

    f32x4 acc[2][4];
    #pragma unroll
    for (int m = 0; m < 2; ++m)
        #pragma unroll
        for (int n = 0; n < 4; ++n) acc[m][n] = (f32x4){0.f, 0.f, 0.f, 0.f};

    const u16* WtW = Wt + (size_t)w * (H_ * E_);

    for (int ek = 0; ek < 16; ++ek) {
        __syncthreads();
        #pragma unroll
        for (int i = 0; i < 4; ++i) {
            int q = tid + i * 256;
            int r = q >> 4, c4 = q & 15;
            float4 v = *reinterpret_cast<const float4*>(
                &x[(size_t)(row0 + r) * E_ + ek * 64 + c4 * 4]);
            ushort4 h4;
            h4.x = f2bf(v.x); h4.y = f2bf(v.y);
            h4.z = f2bf(v.z); h4.w = f2bf(v.w);
            *reinterpret_cast<ushort4*>(&As[r * 72 + c4 * 4]) = h4;
        }
        #pragma unroll
        for (int i = 0; i < 4; ++i) {
            int q = tid + i * 256;
            int h = q >> 3, c8 = q & 7;
            *reinterpret_cast<u16x8*>(&Bs[h * 72 + c8 * 8]) =
                *reinterpret_cast<const u16x8*>(
                    &WtW[(size_t)h * E_ + ek * 64 + c8 * 8]);
        }
        __syncthreads();

        #pragma unroll
        for (int kk = 0; kk < 2; ++kk) {
            bf16x8 af[2];
            #pragma unroll
            for (int m = 0; m < 2; ++m)
                af[m] = *reinterpret_cast<const bf16x8*>(
                    &As[(wm * 32 + m * 16 + l15) * 72 + kk * 32 + g * 8]);
            #pragma unroll
            for (int n = 0; n < 4; ++n) {
                bf16x8 bfr = *reinterpret_cast<const bf16x8*>(
                    &Bs[(wn * 64 + n * 16 + l15) * 72 + kk * 32 + g * 8]);
                #pragma unroll
                for (int m = 0; m < 2; ++m)
                    acc[m][n] = __builtin_amdgcn_mfma_f32_16x16x32_bf16(
                        af[m], bfr, acc[m][n], 0, 0, 0);
            }
        }
    }
    __syncthreads();

    if (w < 2) {
        #pragma unroll
        for (int m = 0; m < 2; ++m)
            #pragma unroll
            for (int n = 0; n < 4; ++n)
                #pragma unroll
                for (int r = 0; r < 4; ++r)
                    S[(wm * 32 + m * 16 + g * 4 + r) * 136 +
                      wn * 64 + n * 16 + l15] = f2bf(acc[m][n][r]);
        __syncthreads();
        u16* __restrict__ outp = (w == 0) ? k_out : q_out;
        #pragma unroll
        for (int i = 0; i < 4; ++i) {
            int q = tid + i * 256;
            int r = q >> 4, c8 = q & 15;
            *reinterpret_cast<u16x8*>(
                &outp[(size_t)(row0 + r) * H_ + c8 * 8]) =
                *reinterpret_cast<const u16x8*>(&S[r * 136 + c8 * 8]);
        }
    } else {
        #pragma unroll
        for (int m = 0; m < 2; ++m)
            #pragma unroll
            for (int n = 0; n < 4; ++n) {
                ushort4 h4;
                h4.x = f2bf(acc[m][n][0]); h4.y = f2bf(acc[m][n][1]);
                h4.z = f2bf(acc[m][n][2]); h4.w = f2bf(acc[m][n][3]);
                *reinterpret_cast<ushort4*>(
                    &S[(wn * 64 + n * 16 + l15) * 72 +
                       wm * 32 + m * 16 + g * 4]) = h4;
            }
        __syncthreads();
        const int vb = row0 >> 11;
        const int t0 = row0 & 2047;
        #pragma unroll
        for (int i = 0; i < 4; ++i) {
            int q = tid + i * 256;
            int h = q >> 3, c8 = q & 7;
            *reinterpret_cast<u16x8*>(
                &vt_out[(size_t)vb * TH_ + (size_t)h * T_ + t0 + c8 * 8]) =
                *reinterpret_cast<const u16x8*>(&S[h * 72 + c8 * 8]);
        }
    }
}

// ---------------------------------------------------------------------------
// Flash attention, bf16 MFMA — round-12 kernel (32 q-rows/wave, 4-way
// in-block split-s, asm-batched VMEM + counted vmcnt, LDS merge) with
// BALANCED CU PAIRING:
//   blocks idx and idx+256 land on the same CU (8-XCD round-robin:
//   same XCD = idx%8, same slot = (idx/8)%32). Map jt so the pair's work
//   sums constant: idx<256 -> jt = 63-p (heavy, dispatched first);
//   idx>=256 -> jt = p-32 (light). Per-CU work = nt(63-p)+nt(p) = 33
//   tile-units for every CU (was 18..48 -> 1.45-2.7x straggler tail).
// grid: 512 = 8 batches (low bits, XCD affinity) x 64 row-tiles.
// ---------------------------------------------------------------------------
__global__ __launch_bounds__(256, 2) void attn_mfma(
    const u16* __restrict__ qg,
    const u16* __restrict__ kg,
    const u16* __restrict__ vtg,
    float* __restrict__ out)
{
    // Pool: loop phase  = Plds u16[4][32][72]            = 18432 B
    //       merge phase = Om f32[4][64][33] (33792 B)
    //                   + Ms f32[4][64][8]  (8192 B) @33792
    //                   + Ls f32[4][64][8]  (8192 B) @41984  -> 50176 B
    __shared__ __align__(16) unsigned char Pool[50176];
    u16 (*Plds)[32][72] = reinterpret_cast<u16 (*)[32][72]>(Pool);

    const int tid  = threadIdx.x;
    const int wave = tid >> 6;
    const int lane = tid & 63;
    const int l15  = lane & 15;
    const int g    = lane >> 4;          // 0..3

    const int b   = blockIdx.x & 7;              // batch -> XCD affinity
    const int p   = blockIdx.x >> 3;             // 0..63
    const int jt  = (p < 32) ? (63 - p) : (p - 32);  // balanced CU pairing
    const int qw0 = jt * 32;                     // block's 32 q rows
    const size_t gbase = (size_t)b * TH_;

    // Q fragments: 2 row-fragments x 4 k-steps (same rows for all 4 waves)
    bf16x8 qf[2][4];
    #pragma unroll
    for (int m = 0; m < 2; ++m)
        #pragma unroll
        for (int ks = 0; ks < 4; ++ks)
            qf[m][ks] = *reinterpret_cast<const bf16x8*>(
                &qg[gbase + (size_t)(qw0 + m * 16 + l15) * H_ + ks * 32 + g * 8]);

    f32x4 oacc[2][8];
    #pragma unroll
    for (int m = 0; m < 2; ++m)
        #pragma unroll
        for (int ht = 0; ht < 8; ++ht) oacc[m][ht] = (f32x4){0.f, 0.f, 0.f, 0.f};
    float m_r[2][4], lsum[2][4];
    #pragma unroll
    for (int m = 0; m < 2; ++m)
        #pragma unroll
        for (int r = 0; r < 4; ++r) { m_r[m][r] = -INFINITY; lsum[m][r] = 0.f; }

    const u16* kbat  = kg  + gbase;
    const u16* vtbat = vtg + gbase;

    const int nt = (jt >> 1) + 1;        // causal s-tiles for this row-tile
    for (int st = wave; st < nt; st += 4) {
        const int s0 = st * 64;
        const u16* kp = kbat + (size_t)s0 * H_;

        // ---- batch-issue 16 K loads via asm (back-to-back, no interleaved waits)
        bf16x8 kf[4][4];
        #pragma unroll
        for (int ks = 0; ks < 4; ++ks)
            #pragma unroll
            for (int t4 = 0; t4 < 4; ++t4) {
                const u16* pk = &kp[(size_t)(t4 * 16 + l15) * H_ + (ks * 4 + g) * 8];
                asm volatile("global_load_dwordx4 %0, %1, off"
                             : "=v"(kf[ks][t4]) : "v"(pk));
            }
        asm volatile("s_waitcnt vmcnt(0)" ::: "memory");
        __builtin_amdgcn_sched_barrier(0);

        // ---- QK^T: 32 MFMA (2 m x 4 ks x 4 t4), K reused across m ----
        f32x4 sa[2][4];
        #pragma unroll
        for (int m = 0; m < 2; ++m)
            #pragma unroll
            for (int t4 = 0; t4 < 4; ++t4) sa[m][t4] = (f32x4){0.f, 0.f, 0.f, 0.f};
        __builtin_amdgcn_s_setprio(1);
        #pragma unroll
        for (int ks = 0; ks < 4; ++ks)
            #pragma unroll
            for (int t4 = 0; t4 < 4; ++t4)
                #pragma unroll
                for (int m = 0; m < 2; ++m)
                    sa[m][t4] = __builtin_amdgcn_mfma_f32_16x16x32_bf16(
                        qf[m][ks], kf[ks][t4], sa[m][t4], 0, 0, 0);
        __builtin_amdgcn_s_setprio(0);

        // ---- batch-issue 16 V loads via asm (V0 then V1); fly under softmax --
        bf16x8 vf0[8], vf1[8];
        #pragma unroll
        for (int ht = 0; ht < 8; ++ht) {
            const u16* pv = &vtbat[(size_t)(ht * 16 + l15) * T_ + s0 + g * 8];
            asm volatile("global_load_dwordx4 %0, %1, off"
                         : "=v"(vf0[ht]) : "v"(pv));
        }
        #pragma unroll
        for (int ht = 0; ht < 8; ++ht) {
            const u16* pv = &vtbat[(size_t)(ht * 16 + l15) * T_ + s0 + (4 + g) * 8];
            asm volatile("global_load_dwordx4 %0, %1, off"
                         : "=v"(vf1[ht]) : "v"(pv));
        }

        // ---- online softmax over 8 rows/lane (2 m x 4 r) ----
        const float scale = 0.088388347648318447f;   // 1/sqrt(128)
        const bool need_mask = (s0 + 63 > qw0);
        float cfac[2][4];
        #pragma unroll
        for (int m = 0; m < 2; ++m) {
            #pragma unroll
            for (int r = 0; r < 4; ++r) {
                const int qrow = qw0 + m * 16 + g * 4 + r;
                float sv[4];
                float mx = -INFINITY;
                #pragma unroll
                for (int t4 = 0; t4 < 4; ++t4) {
                    float s = sa[m][t4][r] * scale;
                    if (need_mask && (s0 + t4 * 16 + l15 > qrow)) s = -INFINITY;
                    sv[t4] = s;
                    mx = fmaxf(mx, s);
                }
                mx = fmaxf(mx, __shfl_xor(mx, 1));
                mx = fmaxf(mx, __shfl_xor(mx, 2));
                mx = fmaxf(mx, __shfl_xor(mx, 4));
                mx = fmaxf(mx, __shfl_xor(mx, 8));
                const float mn = fmaxf(m_r[m][r], mx);
                const float c  = __expf(m_r[m][r] - mn);
                float sum = 0.f;
                #pragma unroll
                for (int t4 = 0; t4 < 4; ++t4) {
                    float pv = __expf(sv[t4] - mn);
                    sum += pv;
                    Plds[wave][m * 16 + g * 4 + r][t4 * 16 + l15] = f2bf(pv);
                }
                sum += __shfl_xor(sum, 1);
                sum += __shfl_xor(sum, 2);
                sum += __shfl_xor(sum, 4);
                sum += __shfl_xor(sum, 8);
                lsum[m][r] = lsum[m][r] * c + sum;
                m_r[m][r]  = mn;
                cfac[m][r] = c;
            }
        }

        // ---- rescale O ----
        #pragma unroll
        for (int m = 0; m < 2; ++m)
            #pragma unroll
            for (int ht = 0; ht < 8; ++ht)
                #pragma unroll
                for (int r = 0; r < 4; ++r) oacc[m][ht][r] *= cfac[m][r];

        // ---- PV half 0: wait V0 only (vmcnt(8) keeps V1 outstanding) ----
        asm volatile("s_waitcnt vmcnt(8)" ::: "memory");
        __builtin_amdgcn_sched_barrier(0);
        #pragma unroll
        for (int m = 0; m < 2; ++m) {
            bf16x8 pa = *reinterpret_cast<const bf16x8*>(
                &Plds[wave][m * 16 + l15][g * 8]);
            __builtin_amdgcn_s_setprio(1);
            #pragma unroll
            for (int ht = 0; ht < 8; ++ht)
                oacc[m][ht] = __builtin_amdgcn_mfma_f32_16x16x32_bf16(
                    pa, vf0[ht], oacc[m][ht], 0, 0, 0);
            __builtin_amdgcn_s_setprio(0);
        }
        // ---- PV half 1 ----
        asm volatile("s_waitcnt vmcnt(0)" ::: "memory");
        __builtin_amdgcn_sched_barrier(0);
        #pragma unroll
        for (int m = 0; m < 2; ++m) {
            bf16x8 pa = *reinterpret_cast<const bf16x8*>(
                &Plds[wave][m * 16 + l15][32 + g * 8]);
            __builtin_amdgcn_s_setprio(1);
            #pragma unroll
            for (int ht = 0; ht < 8; ++ht)
                oacc[m][ht] = __builtin_amdgcn_mfma_f32_16x16x32_bf16(
                    pa, vf1[ht], oacc[m][ht], 0, 0, 0);
            __builtin_amdgcn_s_setprio(0);
        }
    }

    // ---- block-wide split-s merge through LDS, 2 m-passes ----
    __syncthreads();                      // all waves done with Plds -> pool reuse
    {
        float* Om = reinterpret_cast<float*>(Pool);           // [256][33]
        float* Ms = reinterpret_cast<float*>(Pool + 33792);   // [256][8]
        float* Ls = reinterpret_cast<float*>(Pool + 41984);   // [256][8]
        const int wl = wave * 64 + lane;
        #pragma unroll
        for (int m = 0; m < 2; ++m)
            #pragma unroll
            for (int r = 0; r < 4; ++r) {
                Ms[wl * 8 + m * 4 + r] = m_r[m][r];
                Ls[wl * 8 + m * 4 + r] = lsum[m][r];
            }

        #pragma unroll
        for (int m = 0; m < 2; ++m) {
            #pragma unroll
            for (int ht = 0; ht < 8; ++ht)
                #pragma unroll
                for (int r = 0; r < 4; ++r)
                    Om[wl * 33 + ht * 4 + r] = oacc[m][ht][r];
            __syncthreads();

            if (wave == 0) {
                #pragma unroll
                for (int r = 0; r < 4; ++r) {
                    float M = -INFINITY;
                    #pragma unroll
                    for (int w2 = 0; w2 < 4; ++w2)
                        M = fmaxf(M, Ms[(w2 * 64 + lane) * 8 + m * 4 + r]);
                    float wgt[4];
                    float L = 0.f;
                    #pragma unroll
                    for (int w2 = 0; w2 < 4; ++w2) {
                        wgt[w2] = __expf(Ms[(w2 * 64 + lane) * 8 + m * 4 + r] - M);
                        L += Ls[(w2 * 64 + lane) * 8 + m * 4 + r] * wgt[w2];
                    }
                    const float inv = 1.f / L;
                    float* op = &out[gbase + (size_t)(qw0 + m * 16 + g * 4 + r) * H_];
                    #pragma unroll
                    for (int ht = 0; ht < 8; ++ht) {
                        float a = 0.f;
                        #pragma unroll
                        for (int w2 = 0; w2 < 4; ++w2)
                            a += Om[(w2 * 64 + lane) * 33 + ht * 4 + r] * wgt[w2];
                        op[ht * 16 + l15] = a * inv;
                    }
                }
            }
            __syncthreads();              // wave0 done reading Om before overwrite
        }
    }
}

// ---------------------------------------------------------------------------
extern "C" void kernel_launch(void* const* d_in, const int* in_sizes, int n_in,
                              void* d_out, int out_size, void* d_ws, size_t ws_size,
                              hipStream_t stream) {
    const float* x  = (const float*)d_in[0];
    const float* Wk = (const float*)d_in[1];
    const float* Wq = (const float*)d_in[2];
    const float* Wv = (const float*)d_in[3];
    float* out = (float*)d_out;

    u16* k_ws  = (u16*)d_ws;
    u16* q_ws  = k_ws + (size_t)BT_ * H_;
    u16* vt_ws = q_ws + (size_t)BT_ * H_;
    u16* Wt_ws = vt_ws + (size_t)BT_ * H_;

    prep_kernel<<<dim3(24), 256, 0, stream>>>(Wk, Wq, Wv, Wt_ws);

    dim3 pgrid(BT_ / 64, 1, 3);    // z: 0=k, 1=q, 2=v^T
    proj_mfma<<<pgrid, 256, 0, stream>>>(x, Wt_ws, k_ws, q_ws, vt_ws);

    attn_mfma<<<dim3(512), 256, 0, stream>>>(q_ws, k_ws, vt_ws, out);
}